// Round 1
// baseline (601.540 us; speedup 1.0000x reference)
//
#include <hip/hip_runtime.h>

// GlobalInteraction: B=4096, N_GLOBAL=64, D=256, E=4, TPE=16, F=TPE*D=4096
// X:(B,64,256) f32; W1:(E,4096,256); b1:(E,256); W2:(E,256,4096); b2:(E,4096);
// gamma,beta:(E,256). Out:(B,64,256) f32.

typedef __attribute__((ext_vector_type(4))) float f32x4;
typedef __bf16 bf16;
typedef __attribute__((ext_vector_type(8))) bf16 bf16x8;

#define DEV static __device__ __forceinline__

DEV f32x4 zero4() { return f32x4{0.f, 0.f, 0.f, 0.f}; }

// ---------------------------------------------------------------------------
// K0: transpose + cast f32 (R,C) -> bf16 (C,R), per expert (blockIdx.z)
// ---------------------------------------------------------------------------
__global__ void transpose_cast(const float* __restrict__ src,
                               bf16* __restrict__ dst, int R, int C) {
  __shared__ bf16 t[32][33];
  const int e = blockIdx.z;
  const float* s = src + (size_t)e * R * C;
  bf16* d = dst + (size_t)e * R * C;
  const int c0 = blockIdx.x * 32, r0 = blockIdx.y * 32;
  const int tx = threadIdx.x, ty = threadIdx.y;
#pragma unroll
  for (int i = 0; i < 4; i++)
    t[ty + 8 * i][tx] = (bf16)s[(size_t)(r0 + ty + 8 * i) * C + c0 + tx];
  __syncthreads();
#pragma unroll
  for (int i = 0; i < 4; i++)
    d[(size_t)(c0 + ty + 8 * i) * R + r0 + tx] = t[tx][ty + 8 * i];
}

// ---------------------------------------------------------------------------
// K2: attention per (b,e): Y0 = softmax(Xp Xp^T / 16) Xp + Xp  -> d_out (f32)
// One wave per pair. 4 waves per block.
// ---------------------------------------------------------------------------
__global__ __launch_bounds__(256) void attn_kernel(const float* __restrict__ X,
                                                   float* __restrict__ Y0) {
  // per-wave scratch: Xp^T [256+pad rows][16] bf16, P [16][32] bf16 (k>=16 zero)
  __shared__ __align__(16) bf16 XpT[4][4160];
  __shared__ __align__(16) bf16 Pl[4][512];
  const int tid = threadIdx.x, lane = tid & 63, w = tid >> 6;
  const int lr = lane & 15, g = lane >> 4;
  bf16* xt = XpT[w];
  bf16* pl = Pl[w];

  // zero pad regions (per-wave private; no barriers needed anywhere here)
  for (int q = lane; q < 256; q += 64) {        // P cols 16..31
    int row = q >> 4, cc = q & 15;
    pl[row * 32 + 16 + cc] = (bf16)0.f;
  }
  xt[4096 + lane] = (bf16)0.f;                  // XpT tail pad (reads < 4112)

  const int p = blockIdx.x * 4 + w;             // pair id
  const int b = p >> 2, e = p & 3;
  const float* Xb = X + (size_t)b * 16384 + e * 4096;
  float* Yb = Y0 + (size_t)b * 16384 + e * 4096;

  // Load Xp as A-frags (lane: token lr, k = 32c+8g+j) and write Xp^T to LDS
  bf16x8 af[8];
#pragma unroll
  for (int c = 0; c < 8; c++) {
    const float* q = Xb + lr * 256 + c * 32 + g * 8;
    f32x4 v0 = *(const f32x4*)q;
    f32x4 v1 = *(const f32x4*)(q + 4);
    bf16x8 o;
    o[0] = (bf16)v0.x; o[1] = (bf16)v0.y; o[2] = (bf16)v0.z; o[3] = (bf16)v0.w;
    o[4] = (bf16)v1.x; o[5] = (bf16)v1.y; o[6] = (bf16)v1.z; o[7] = (bf16)v1.w;
    af[c] = o;
#pragma unroll
    for (int j = 0; j < 8; j++)
      xt[(c * 32 + g * 8 + j) * 16 + lr] = o[j];  // XpT[d][m]
  }

  // scores = Xp Xp^T : B-frag of Xp^T == A-frag of Xp (same registers)
  f32x4 s = zero4();
#pragma unroll
  for (int c = 0; c < 8; c++)
    s = __builtin_amdgcn_mfma_f32_16x16x32_bf16(af[c], af[c], s, 0, 0, 0);

  // softmax per row t = 4g+r over m = lr (reduce across the 16-lane group)
  float pv[4];
#pragma unroll
  for (int r = 0; r < 4; r++) {
    float v = s[r] * 0.0625f;
    float mx = v;
#pragma unroll
    for (int m = 1; m < 16; m <<= 1) mx = fmaxf(mx, __shfl_xor(mx, m));
    float ev = __expf(v - mx);
    float sum = ev;
#pragma unroll
    for (int m = 1; m < 16; m <<= 1) sum += __shfl_xor(sum, m);
    pv[r] = ev / sum;
  }
  // P[t][m] -> LDS (bf16), rows t=4g+r, col m=lr
#pragma unroll
  for (int r = 0; r < 4; r++) pl[(g * 4 + r) * 32 + lr] = (bf16)pv[r];

  // P A-frag (K padded to 32; k>=16 are zeros)
  bf16x8 pf = *(const bf16x8*)&pl[lr * 32 + g * 8];

  // X_dot = P @ Xp, 16-col chunks; epilogue: Y0 = X_dot + Xp
#pragma unroll
  for (int nc = 0; nc < 16; nc++) {
    bf16x8 bfr = *(const bf16x8*)&xt[(nc * 16 + lr) * 16 + g * 8];
    f32x4 xd = __builtin_amdgcn_mfma_f32_16x16x32_bf16(pf, bfr, zero4(), 0, 0, 0);
#pragma unroll
    for (int r = 0; r < 4; r++) {
      int idx = (g * 4 + r) * 256 + nc * 16 + lr;
      Yb[idx] = xd[r] + Xb[idx];
    }
  }
}

// ---------------------------------------------------------------------------
// K1: H[b,e,:] = relu(Xf @ W1[e] + b1[e]),  M=64/block, N=256, K=4096 (BK=64)
// ---------------------------------------------------------------------------
__global__ __launch_bounds__(512) void gemm1_kernel(
    const float* __restrict__ X, const bf16* __restrict__ W1T,
    const float* __restrict__ b1, bf16* __restrict__ H) {
  __shared__ __align__(16) bf16 Ab[64 * 72];    // [64 rows][64+8 k]
  __shared__ __align__(16) bf16 Bt[256 * 72];   // [256 n][64+8 k]
  const int e = blockIdx.y;
  const int b0 = blockIdx.x * 64;
  const int tid = threadIdx.x, lane = tid & 63, w = tid >> 6;
  const int wm = w >> 2, wn = w & 3;            // waves 2(m) x 4(n)
  const int lr = lane & 15, g = lane >> 4;

  const float* Xb = X + (size_t)b0 * 16384 + e * 4096;
  const bf16* Wb = W1T + (size_t)e * (256 * 4096);

  f32x4 acc[2][4];
#pragma unroll
  for (int i = 0; i < 2; i++)
#pragma unroll
    for (int j = 0; j < 4; j++) acc[i][j] = zero4();

  const int arow = tid >> 3, ak0 = (tid & 7) * 8;

  for (int kt = 0; kt < 64; kt++) {
    {  // stage A (f32 -> bf16): 64 x 64
      const float* q = Xb + (size_t)arow * 16384 + kt * 64 + ak0;
      f32x4 v0 = *(const f32x4*)q;
      f32x4 v1 = *(const f32x4*)(q + 4);
      bf16x8 o;
      o[0] = (bf16)v0.x; o[1] = (bf16)v0.y; o[2] = (bf16)v0.z; o[3] = (bf16)v0.w;
      o[4] = (bf16)v1.x; o[5] = (bf16)v1.y; o[6] = (bf16)v1.z; o[7] = (bf16)v1.w;
      *(bf16x8*)&Ab[arow * 72 + ak0] = o;
    }
#pragma unroll
    for (int p = 0; p < 4; p++) {  // stage B (already bf16): 256 n x 64 k
      int idx = p * 512 + tid;
      int n = idx >> 3, k0 = (idx & 7) * 8;
      bf16x8 v = *(const bf16x8*)&Wb[(size_t)n * 4096 + kt * 64 + k0];
      *(bf16x8*)&Bt[n * 72 + k0] = v;
    }
    __syncthreads();
#pragma unroll
    for (int kk = 0; kk < 2; kk++) {
      bf16x8 afr[2], bfr[4];
#pragma unroll
      for (int i = 0; i < 2; i++)
        afr[i] = *(const bf16x8*)&Ab[(wm * 32 + i * 16 + lr) * 72 + kk * 32 + g * 8];
#pragma unroll
      for (int j = 0; j < 4; j++)
        bfr[j] = *(const bf16x8*)&Bt[(wn * 64 + j * 16 + lr) * 72 + kk * 32 + g * 8];
#pragma unroll
      for (int i = 0; i < 2; i++)
#pragma unroll
        for (int j = 0; j < 4; j++)
          acc[i][j] = __builtin_amdgcn_mfma_f32_16x16x32_bf16(afr[i], bfr[j],
                                                              acc[i][j], 0, 0, 0);
    }
    __syncthreads();
  }
  // epilogue: relu(acc + b1) -> H bf16, H layout (B, E, 256)
#pragma unroll
  for (int j = 0; j < 4; j++) {
    int col = wn * 64 + j * 16 + lr;
    float bv = b1[e * 256 + col];
#pragma unroll
    for (int i = 0; i < 2; i++)
#pragma unroll
      for (int r = 0; r < 4; r++) {
        int row = wm * 32 + i * 16 + g * 4 + r;
        float v = fmaxf(acc[i][j][r] + bv, 0.f);
        H[((size_t)(b0 + row) * 4 + e) * 256 + col] = (bf16)v;
      }
  }
}

// ---------------------------------------------------------------------------
// K3: X_deep = H @ W2[e] + b2; Y = Y0 + X_deep; LayerNorm(D=256) -> Out (f32)
// Block: 64 b-rows x one expert; loop over 16 tokens (256-wide n-chunks).
// ---------------------------------------------------------------------------
__global__ __launch_bounds__(512) void gemm2_kernel(
    const bf16* __restrict__ H, const bf16* __restrict__ W2T,
    const float* __restrict__ b2, const float* __restrict__ gamma,
    const float* __restrict__ beta, float* __restrict__ Out) {
  __shared__ __align__(16) bf16 Ah[64 * 264];   // [64 b][256+8 k]
  __shared__ __align__(16) bf16 Bt[256 * 72];   // [256 n][64+8 k]
  __shared__ float reds[64 * 4], redq[64 * 4];
  __shared__ float muL[64], rsL[64];
  const int e = blockIdx.y, b0 = blockIdx.x * 64;
  const int tid = threadIdx.x, lane = tid & 63, w = tid >> 6;
  const int wm = w >> 2, wn = w & 3;
  const int lr = lane & 15, g = lane >> 4;

  // stage full H tile (64 x 256 bf16)
#pragma unroll
  for (int p = 0; p < 4; p++) {
    int idx = p * 512 + tid;
    int row = idx >> 5, k0 = (idx & 31) * 8;
    bf16x8 v = *(const bf16x8*)&H[((size_t)(b0 + row) * 4 + e) * 256 + k0];
    *(bf16x8*)&Ah[row * 264 + k0] = v;
  }
  __syncthreads();

  // preload all A-frags (K=256 -> 8 chunks per m-frag)
  bf16x8 afr[2][8];
#pragma unroll
  for (int i = 0; i < 2; i++)
#pragma unroll
    for (int c = 0; c < 8; c++)
      afr[i][c] = *(const bf16x8*)&Ah[(wm * 32 + i * 16 + lr) * 264 + c * 32 + g * 8];

  float gv[4], btv[4];
#pragma unroll
  for (int j = 0; j < 4; j++) {
    int col = wn * 64 + j * 16 + lr;
    gv[j] = gamma[e * 256 + col];
    btv[j] = beta[e * 256 + col];
  }
  const bf16* Wb = W2T + (size_t)e * (4096 * 256);

  for (int t = 0; t < 16; t++) {
    f32x4 acc[2][4];
#pragma unroll
    for (int i = 0; i < 2; i++)
#pragma unroll
      for (int j = 0; j < 4; j++) acc[i][j] = zero4();

    for (int kt = 0; kt < 4; kt++) {
      __syncthreads();  // prior Bt readers / prior epilogue done
#pragma unroll
      for (int p = 0; p < 4; p++) {  // stage W2T chunk: 256 n x 64 k
        int idx = p * 512 + tid;
        int n = idx >> 3, k0 = (idx & 7) * 8;
        bf16x8 v = *(const bf16x8*)&Wb[(size_t)(t * 256 + n) * 256 + kt * 64 + k0];
        *(bf16x8*)&Bt[n * 72 + k0] = v;
      }
      __syncthreads();
#pragma unroll
      for (int kk = 0; kk < 2; kk++) {
        bf16x8 bfr[4];
#pragma unroll
        for (int j = 0; j < 4; j++)
          bfr[j] = *(const bf16x8*)&Bt[(wn * 64 + j * 16 + lr) * 72 + kk * 32 + g * 8];
#pragma unroll
        for (int i = 0; i < 2; i++)
#pragma unroll
          for (int j = 0; j < 4; j++)
            acc[i][j] = __builtin_amdgcn_mfma_f32_16x16x32_bf16(
                afr[i][kt * 2 + kk], bfr[j], acc[i][j], 0, 0, 0);
      }
    }
    // epilogue: y = acc + b2 + Y0; LayerNorm over 256 cols of each row
    float b2v[4];
#pragma unroll
    for (int j = 0; j < 4; j++)
      b2v[j] = b2[e * 4096 + t * 256 + wn * 64 + j * 16 + lr];

    float y[2][4][4];
#pragma unroll
    for (int i = 0; i < 2; i++)
#pragma unroll
      for (int r = 0; r < 4; r++) {
        int row = wm * 32 + i * 16 + g * 4 + r;
        size_t obase = (size_t)(b0 + row) * 16384 + e * 4096 + t * 256;
        float s1 = 0.f, s2 = 0.f;
#pragma unroll
        for (int j = 0; j < 4; j++) {
          int col = wn * 64 + j * 16 + lr;
          float v = acc[i][j][r] + b2v[j] + Out[obase + col];
          y[i][j][r] = v;
          s1 += v;
          s2 += v * v;
        }
#pragma unroll
        for (int m = 1; m < 16; m <<= 1) {
          s1 += __shfl_xor(s1, m);
          s2 += __shfl_xor(s2, m);
        }
        if (lr == 0) {
          reds[row * 4 + wn] = s1;
          redq[row * 4 + wn] = s2;
        }
      }
    __syncthreads();
    if (tid < 64) {
      float s1 = reds[tid * 4] + reds[tid * 4 + 1] + reds[tid * 4 + 2] + reds[tid * 4 + 3];
      float s2 = redq[tid * 4] + redq[tid * 4 + 1] + redq[tid * 4 + 2] + redq[tid * 4 + 3];
      float mu = s1 * (1.f / 256.f);
      float var = s2 * (1.f / 256.f) - mu * mu;
      muL[tid] = mu;
      rsL[tid] = rsqrtf(var + 1e-5f);
    }
    __syncthreads();
#pragma unroll
    for (int i = 0; i < 2; i++)
#pragma unroll
      for (int r = 0; r < 4; r++) {
        int row = wm * 32 + i * 16 + g * 4 + r;
        float mu = muL[row], rs = rsL[row];
        size_t obase = (size_t)(b0 + row) * 16384 + e * 4096 + t * 256;
#pragma unroll
        for (int j = 0; j < 4; j++) {
          int col = wn * 64 + j * 16 + lr;
          Out[obase + col] = (y[i][j][r] - mu) * rs * gv[j] + btv[j];
        }
      }
  }
}

// ---------------------------------------------------------------------------
extern "C" void kernel_launch(void* const* d_in, const int* in_sizes, int n_in,
                              void* d_out, int out_size, void* d_ws, size_t ws_size,
                              hipStream_t stream) {
  const float* X     = (const float*)d_in[0];
  const float* W1    = (const float*)d_in[1];
  const float* b1    = (const float*)d_in[2];
  const float* W2    = (const float*)d_in[3];
  const float* b2    = (const float*)d_in[4];
  const float* gamma = (const float*)d_in[5];
  const float* beta  = (const float*)d_in[6];
  float* Out = (float*)d_out;

  bf16* W1T = (bf16*)d_ws;                 // (E,256,4096) bf16 : 8 MB
  bf16* W2T = W1T + (size_t)4 * 1048576;   // (E,4096,256) bf16 : 8 MB
  bf16* H   = W2T + (size_t)4 * 1048576;   // (B,E,256)    bf16 : 8 MB

  transpose_cast<<<dim3(8, 128, 4), dim3(32, 8), 0, stream>>>(W1, W1T, 4096, 256);
  transpose_cast<<<dim3(128, 8, 4), dim3(32, 8), 0, stream>>>(W2, W2T, 256, 4096);
  attn_kernel<<<dim3(4096), dim3(256), 0, stream>>>(X, Out);          // Y0 -> Out
  gemm1_kernel<<<dim3(64, 4), dim3(512), 0, stream>>>(X, W1T, b1, H);
  gemm2_kernel<<<dim3(64, 4), dim3(512), 0, stream>>>(H, W2T, b2, gamma, beta, Out);
}